// Round 9
// baseline (485.049 us; speedup 1.0000x reference)
//
#include <hip/hip_runtime.h>
#include <stdint.h>

// B=2,S=2048,D=1024,H=16,R=64,N=32,RK=128,DH=64. Tokens T=4096.

typedef __bf16 bf16x8 __attribute__((ext_vector_type(8)));
typedef float f32x4 __attribute__((ext_vector_type(4)));

__device__ __forceinline__ unsigned short f2b(float f) {
  union { float f; unsigned u; } v; v.f = f;
  unsigned u = v.u;
  unsigned r = (u + 0x7FFFu + ((u >> 16) & 1u)) >> 16;  // RNE
  return (unsigned short)r;
}
__device__ __forceinline__ float b2f(unsigned short h) {
  union { unsigned u; float f; } v; v.u = ((unsigned)h) << 16;
  return v.f;
}
__device__ __forceinline__ unsigned pk2(float lo, float hi) {
  return (unsigned)f2b(lo) | ((unsigned)f2b(hi) << 16);
}
// truncation pack: one v_perm_b32 (bytes: [hi.b3, hi.b2, lo.b3, lo.b2])
__device__ __forceinline__ unsigned pkt(float lo, float hi) {
  union { float f; unsigned u; } a, b; a.f = lo; b.f = hi;
  return __builtin_amdgcn_perm(b.u, a.u, 0x07060302u);
}
__device__ __forceinline__ f32x4 vmax4(f32x4 a, f32x4 b) {
  f32x4 r;
  r[0] = fmaxf(a[0], b[0]); r[1] = fmaxf(a[1], b[1]);
  r[2] = fmaxf(a[2], b[2]); r[3] = fmaxf(a[3], b[3]);
  return r;
}

// ---------------------------------------------------------------------------
// 256x256-tile bf16 GEMM, BK=64, 8 waves (512 thr), 8-PHASE schedule (m201
// template): per phase {ds-read A-quadrant (+B at tile start) || stage one
// half-tile -> s_barrier -> lgkmcnt(0) -> 16 MFMA -> s_barrier}. One
// iteration covers 2 K-tiles (buffers 0/1 fixed even/odd). vmcnt(6) only at
// iteration top and mid (ph4->ph5); never drains in the main loop.
// C[M,N] = A[M,K] @ Bt[N,K]^T, M=N=4096. 256 blocks = 1/CU. K%128==0.
// ---------------------------------------------------------------------------
#define MFMA_BF16 __builtin_amdgcn_mfma_f32_16x16x32_bf16

#define PHASE8(TB, MQ, STAGE) { \
  const int ra = (wr * 128 + (MQ) * 32 + l16) * 64; \
  const bf16x8 a00 = *(const bf16x8*)&lsA[TB][ra + sl0]; \
  const bf16x8 a01 = *(const bf16x8*)&lsA[TB][ra + sl1]; \
  const bf16x8 a10 = *(const bf16x8*)&lsA[TB][ra + 16 * 64 + sl0]; \
  const bf16x8 a11 = *(const bf16x8*)&lsA[TB][ra + 16 * 64 + sl1]; \
  STAGE; \
  __builtin_amdgcn_s_barrier(); \
  asm volatile("s_waitcnt lgkmcnt(0)" ::: "memory"); \
  __builtin_amdgcn_s_setprio(1); \
  _Pragma("unroll") \
  for (int n = 0; n < 4; ++n) { \
    acc[(MQ) * 2][n]     = MFMA_BF16(a00, bfr[n][0], acc[(MQ) * 2][n], 0, 0, 0); \
    acc[(MQ) * 2][n]     = MFMA_BF16(a01, bfr[n][1], acc[(MQ) * 2][n], 0, 0, 0); \
    acc[(MQ) * 2 + 1][n] = MFMA_BF16(a10, bfr[n][0], acc[(MQ) * 2 + 1][n], 0, 0, 0); \
    acc[(MQ) * 2 + 1][n] = MFMA_BF16(a11, bfr[n][1], acc[(MQ) * 2 + 1][n], 0, 0, 0); \
  } \
  __builtin_amdgcn_s_setprio(0); }

#define LOADB(TB) { \
  _Pragma("unroll") \
  for (int n = 0; n < 4; ++n) { \
    const int rb_ = (wc * 64 + n * 16 + l16) * 64; \
    bfr[n][0] = *(const bf16x8*)&lsB[TB][rb_ + sl0]; \
    bfr[n][1] = *(const bf16x8*)&lsB[TB][rb_ + sl1]; \
  } }

__global__ __launch_bounds__(512, 2) void gemm_bt256(
    const unsigned short* __restrict__ A, const unsigned short* __restrict__ Bt,
    unsigned short* __restrict__ out, int K) {
  __shared__ unsigned short lsA[2][256 * 64];
  __shared__ unsigned short lsB[2][256 * 64];
  const int N = 4096;
  const int bid = blockIdx.x;
  const int xcd = bid & 7, j = bid >> 3;
  const int row0 = (xcd * 2 + (j >> 4)) * 256;
  const int col0 = (j & 15) * 256;
  const int tid = threadIdx.x;
  const int w = tid >> 6, lane = tid & 63;
  const int quad = lane >> 4, l16 = lane & 15;
  const int wr = w >> 2, wc = w & 3;

  const int scg = ((lane & 7) ^ (lane >> 3)) * 8;
  const unsigned short* apg = A + (size_t)(row0 + w * 8 + (lane >> 3)) * K + scg;
  const unsigned short* bpg = Bt + (size_t)(col0 + w * 8 + (lane >> 3)) * K + scg;

  const int sl0 = (quad ^ (l16 & 7)) * 8;
  const int sl1 = ((4 + quad) ^ (l16 & 7)) * 8;

  const f32x4 fz = {0.f, 0.f, 0.f, 0.f};
  f32x4 acc[8][4];
#pragma unroll
  for (int m = 0; m < 8; ++m)
#pragma unroll
    for (int n = 0; n < 4; ++n) acc[m][n] = fz;

  // stage A half h (X=0: rows {0..63}u{128..191}; Y=1: +64) of K-chunk k0
  auto stA = [&](int b, int h, int k0) {
#pragma unroll
    for (int jj = 0; jj < 2; ++jj)
      __builtin_amdgcn_global_load_lds(
          (const __attribute__((address_space(1))) unsigned int*)(apg + (size_t)(jj * 128 + h * 64) * K + k0),
          (__attribute__((address_space(3))) unsigned int*)&lsA[b][(jj * 128 + h * 64 + w * 8) * 64],
          16, 0, 0);
  };
  // stage B half h (lo=0: rows 0..127; hi=1: 128..255)
  auto stB = [&](int b, int h, int k0) {
#pragma unroll
    for (int jj = 0; jj < 2; ++jj)
      __builtin_amdgcn_global_load_lds(
          (const __attribute__((address_space(1))) unsigned int*)(bpg + (size_t)(h * 128 + jj * 64) * K + k0),
          (__attribute__((address_space(3))) unsigned int*)&lsB[b][(h * 128 + jj * 64 + w * 8) * 64],
          16, 0, 0);
  };

  const int P = K >> 7;  // pairs of K-tiles (K % 128 == 0)
  // prologue FIFO: B0lo,B0hi,A0X,A0Y | B1lo,B1hi,A1X   (A1Y staged in iter0.ph1)
  stB(0, 0, 0); stB(0, 1, 0); stA(0, 0, 0); stA(0, 1, 0);
  stB(1, 0, 64); stB(1, 1, 64); stA(1, 0, 64);

  bf16x8 bfr[4][2];
  for (int i = 0; i < P; ++i) {
    const int kb = (2 * i + 1) << 6;          // current tile-b K offset
    const int ka2 = (2 * i + 2) << 6;         // next pair
    const int kb2 = (2 * i + 3) << 6;
    const bool pf = (i + 1 < P);
    // iteration top: W1
    asm volatile("s_waitcnt vmcnt(6)" ::: "memory");
    __builtin_amdgcn_s_barrier();
    // ---- tile a (buf 0) ----
    LOADB(0)
    PHASE8(0, 0, stA(1, 1, kb))                        // A_Y of current tile b
    __builtin_amdgcn_s_barrier();
    PHASE8(0, 1, if (pf) stB(0, 0, ka2))
    __builtin_amdgcn_s_barrier();
    PHASE8(0, 2, if (pf) stB(0, 1, ka2))
    __builtin_amdgcn_s_barrier();
    PHASE8(0, 3, if (pf) stA(0, 0, ka2))
    // mid: W2 (covers i.ph1's A_Y(b) with 3 newer slots in flight)
    if (pf) { asm volatile("s_waitcnt vmcnt(6)" ::: "memory"); }
    else    { asm volatile("s_waitcnt vmcnt(0)" ::: "memory"); }
    __builtin_amdgcn_s_barrier();
    // ---- tile b (buf 1) ----
    LOADB(1)
    PHASE8(1, 0, if (pf) stA(0, 1, ka2))
    __builtin_amdgcn_s_barrier();
    PHASE8(1, 1, if (pf) stB(1, 0, kb2))
    __builtin_amdgcn_s_barrier();
    PHASE8(1, 2, if (pf) stB(1, 1, kb2))
    __builtin_amdgcn_s_barrier();
    PHASE8(1, 3, if (pf) stA(1, 0, kb2))
    __builtin_amdgcn_s_barrier();
  }

  const int rb = row0 + wr * 128;
  const int cb = col0 + wc * 64;
#pragma unroll
  for (int m = 0; m < 8; ++m) {
#pragma unroll
    for (int n = 0; n < 4; ++n) {
      const int r = rb + m * 16 + quad * 4;
      const int c = cb + n * 16 + l16;
#pragma unroll
      for (int i = 0; i < 4; ++i)
        out[(size_t)(r + i) * N + c] = f2b(acc[m][n][i]);
    }
  }
}

// ---------------------------------------------------------------------------
// Fused Q/K (full-K, direct write) + V restore GEMM. 768 blocks, uniform work.
// fp32 accumulation end-to-end. 768 = 3 blocks/CU exactly with (256,3).
// ---------------------------------------------------------------------------
__global__ __launch_bounds__(256, 3) void gemm_qkv(
    const unsigned short* __restrict__ t_qk, const unsigned short* __restrict__ t_v,
    const unsigned short* __restrict__ r_qkT, const unsigned short* __restrict__ r_vT,
    unsigned short* __restrict__ QK, unsigned short* __restrict__ VT) {
  __shared__ unsigned short lsA[128 * 64];
  __shared__ unsigned short lsB[128 * 64];
  const int K = 2048;
  const int bid = blockIdx.x;
  const unsigned short* A;
  const unsigned short* Bt;
  int row0, col0, isv;
  if (bid < 256) {  // V restore: [4096,2048]@[1024,2048]^T -> VT (transposed)
    const int xcd = bid & 7, j = bid >> 3;
    row0 = (xcd * 4 + (j >> 3)) * 128;
    col0 = (j & 7) * 128;
    A = t_v; Bt = r_vT; isv = 1;
  } else {          // QK: [8192,2048]@[1024,2048]^T -> QKbuf direct
    const int u = bid - 256;
    const int xcd = u & 7, j = u >> 3;
    row0 = (xcd * 8 + (j >> 3)) * 128;
    col0 = (j & 7) * 128;
    A = t_qk; Bt = r_qkT; isv = 0;
  }
  const int tid = threadIdx.x;
  const int w = tid >> 6, lane = tid & 63;
  const int quad = lane >> 4, l16 = lane & 15;
  const int wr = w >> 1, wc = w & 1;

  const int srow = w * 32 + (lane >> 3);
  const int scg = ((lane & 7) ^ (lane >> 3)) * 8;
  const unsigned short* ap = A + (size_t)(row0 + srow) * K + scg;
  const unsigned short* bp = Bt + (size_t)(col0 + srow) * K + scg;

  const f32x4 fz = {0.f, 0.f, 0.f, 0.f};
  f32x4 acc[4][4];
#pragma unroll
  for (int i = 0; i < 4; ++i)
#pragma unroll
    for (int jj = 0; jj < 4; ++jj) acc[i][jj] = fz;

  for (int k0 = 0; k0 < K; k0 += 64) {
#pragma unroll
    for (int i = 0; i < 4; ++i) {
      __builtin_amdgcn_global_load_lds(
          (const __attribute__((address_space(1))) unsigned int*)(ap + (size_t)i * 8 * K + k0),
          (__attribute__((address_space(3))) unsigned int*)&lsA[(w * 32 + i * 8) * 64],
          16, 0, 0);
      __builtin_amdgcn_global_load_lds(
          (const __attribute__((address_space(1))) unsigned int*)(bp + (size_t)i * 8 * K + k0),
          (__attribute__((address_space(3))) unsigned int*)&lsB[(w * 32 + i * 8) * 64],
          16, 0, 0);
    }
    __syncthreads();
#pragma unroll
    for (int kk = 0; kk < 2; ++kk) {
      bf16x8 af[4], bfr[4];
      const int sl = (((kk * 4 + quad) ^ (l16 & 7)) * 8);
#pragma unroll
      for (int mt = 0; mt < 4; ++mt)
        af[mt] = *(const bf16x8*)&lsA[(wr * 64 + mt * 16 + l16) * 64 + sl];
#pragma unroll
      for (int nt = 0; nt < 4; ++nt)
        bfr[nt] = *(const bf16x8*)&lsB[(wc * 64 + nt * 16 + l16) * 64 + sl];
#pragma unroll
      for (int mt = 0; mt < 4; ++mt)
#pragma unroll
        for (int nt = 0; nt < 4; ++nt)
          acc[mt][nt] = __builtin_amdgcn_mfma_f32_16x16x32_bf16(af[mt], bfr[nt], acc[mt][nt], 0, 0, 0);
    }
    __syncthreads();
  }

  const int rb = row0 + wr * 64;
  const int cb = col0 + wc * 64;
#pragma unroll
  for (int mt = 0; mt < 4; ++mt) {
#pragma unroll
    for (int nt = 0; nt < 4; ++nt) {
      const int r = rb + mt * 16 + quad * 4;
      const int c = cb + nt * 16 + l16;
#pragma unroll
      for (int i = 0; i < 4; ++i) {
        const float v = acc[mt][nt][i];
        if (isv) VT[(size_t)c * 4096 + (r + i)] = f2b(v);
        else QK[(size_t)(r + i) * 1024 + c] = f2b(v);
      }
    }
  }
}

// ---------------------------------------------------------------------------
// Split-K x3 GEMM -> fp32 partials. M=4096, N=1024, K=4096 fixed.
// 768 blocks = 32 rows x 8 cols x 3 ks, XCD-banded -> exactly 3 blocks/CU,
// one packed round. K chunks 1344/1344/1408.
// ---------------------------------------------------------------------------
__global__ __launch_bounds__(256, 3) void gemm_ks3(
    const unsigned short* __restrict__ A, const unsigned short* __restrict__ Bt,
    float* __restrict__ p0, float* __restrict__ p1, float* __restrict__ p2) {
  __shared__ unsigned short lsA[128 * 64];
  __shared__ unsigned short lsB[128 * 64];
  const int N = 1024, K = 4096;
  const int bid = blockIdx.x;
  const int xcd = bid & 7, j = bid >> 3;          // j in [0,96)
  const int row_l = j / 24, rem = j % 24;          // 4 rows per xcd
  const int ks = rem >> 3, col = rem & 7;          // 3 ks x 8 cols
  const int row0 = (xcd * 4 + row_l) * 128;
  const int col0 = col * 128;
  const int kbeg = (ks == 0) ? 0 : (ks == 1) ? 1344 : 2688;
  const int kend = (ks == 0) ? 1344 : (ks == 1) ? 2688 : 4096;
  const int tid = threadIdx.x;
  const int w = tid >> 6, lane = tid & 63;
  const int quad = lane >> 4, l16 = lane & 15;
  const int wr = w >> 1, wc = w & 1;

  const int srow = w * 32 + (lane >> 3);
  const int scg = ((lane & 7) ^ (lane >> 3)) * 8;
  const unsigned short* ap = A + (size_t)(row0 + srow) * K + scg;
  const unsigned short* bp = Bt + (size_t)(col0 + srow) * K + scg;

  const f32x4 fz = {0.f, 0.f, 0.f, 0.f};
  f32x4 acc[4][4];
#pragma unroll
  for (int i = 0; i < 4; ++i)
#pragma unroll
    for (int jj = 0; jj < 4; ++jj) acc[i][jj] = fz;

  for (int k0 = kbeg; k0 < kend; k0 += 64) {
#pragma unroll
    for (int i = 0; i < 4; ++i) {
      __builtin_amdgcn_global_load_lds(
          (const __attribute__((address_space(1))) unsigned int*)(ap + (size_t)i * 8 * K + k0),
          (__attribute__((address_space(3))) unsigned int*)&lsA[(w * 32 + i * 8) * 64],
          16, 0, 0);
      __builtin_amdgcn_global_load_lds(
          (const __attribute__((address_space(1))) unsigned int*)(bp + (size_t)i * 8 * K + k0),
          (__attribute__((address_space(3))) unsigned int*)&lsB[(w * 32 + i * 8) * 64],
          16, 0, 0);
    }
    __syncthreads();
#pragma unroll
    for (int kk = 0; kk < 2; ++kk) {
      bf16x8 af[4], bfr[4];
      const int sl = (((kk * 4 + quad) ^ (l16 & 7)) * 8);
#pragma unroll
      for (int mt = 0; mt < 4; ++mt)
        af[mt] = *(const bf16x8*)&lsA[(wr * 64 + mt * 16 + l16) * 64 + sl];
#pragma unroll
      for (int nt = 0; nt < 4; ++nt)
        bfr[nt] = *(const bf16x8*)&lsB[(wc * 64 + nt * 16 + l16) * 64 + sl];
#pragma unroll
      for (int mt = 0; mt < 4; ++mt)
#pragma unroll
        for (int nt = 0; nt < 4; ++nt)
          acc[mt][nt] = __builtin_amdgcn_mfma_f32_16x16x32_bf16(af[mt], bfr[nt], acc[mt][nt], 0, 0, 0);
    }
    __syncthreads();
  }

  float* out = (ks == 0) ? p0 : (ks == 1) ? p1 : p2;
  const int rb = row0 + wr * 64;
  const int cb = col0 + wc * 64;
#pragma unroll
  for (int mt = 0; mt < 4; ++mt) {
#pragma unroll
    for (int nt = 0; nt < 4; ++nt) {
      const int r = rb + mt * 16 + quad * 4;
      const int c = cb + nt * 16 + l16;
#pragma unroll
      for (int i = 0; i < 4; ++i)
        out[(size_t)(r + i) * N + c] = acc[mt][nt][i];
    }
  }
}

// ---------------------------------------------------------------------------
// W_O GEMM with fused residual: x1 = attn @ WO^T + x. 128x64 tiles, no split-K.
// M=4096, N=1024, K=1024 -> 512 blocks (2/CU), fp32 out.
// ---------------------------------------------------------------------------
__global__ __launch_bounds__(256) void gemm_wo_res(
    const unsigned short* __restrict__ A, const unsigned short* __restrict__ Bt,
    const float* __restrict__ res, float* __restrict__ out) {
  __shared__ unsigned short lsA[128 * 64];
  __shared__ unsigned short lsB[64 * 64];
  const int K = 1024, N = 1024;
  const int bid = blockIdx.x;
  const int xcd = bid & 7, j = bid >> 3;
  const int row0 = (xcd * 4 + (j & 3)) * 128;   // 32 row-blocks
  const int col0 = (j >> 2) * 64;               // 16 col-blocks
  const int tid = threadIdx.x;
  const int w = tid >> 6, lane = tid & 63;
  const int quad = lane >> 4, l16 = lane & 15;
  const int wr = w >> 1, wc = w & 1;

  const int srowA = w * 32 + (lane >> 3);
  const int srowB = w * 16 + (lane >> 3);
  const int scg = ((lane & 7) ^ (lane >> 3)) * 8;
  const unsigned short* ap = A + (size_t)(row0 + srowA) * K + scg;
  const unsigned short* bp = Bt + (size_t)(col0 + srowB) * K + scg;

  const f32x4 fz = {0.f, 0.f, 0.f, 0.f};
  f32x4 acc[4][2];
#pragma unroll
  for (int i = 0; i < 4; ++i)
#pragma unroll
    for (int jj = 0; jj < 2; ++jj) acc[i][jj] = fz;

  for (int k0 = 0; k0 < K; k0 += 64) {
#pragma unroll
    for (int i = 0; i < 4; ++i)
      __builtin_amdgcn_global_load_lds(
          (const __attribute__((address_space(1))) unsigned int*)(ap + (size_t)i * 8 * K + k0),
          (__attribute__((address_space(3))) unsigned int*)&lsA[(w * 32 + i * 8) * 64],
          16, 0, 0);
#pragma unroll
    for (int i = 0; i < 2; ++i)
      __builtin_amdgcn_global_load_lds(
          (const __attribute__((address_space(1))) unsigned int*)(bp + (size_t)i * 8 * K + k0),
          (__attribute__((address_space(3))) unsigned int*)&lsB[(w * 16 + i * 8) * 64],
          16, 0, 0);
    __syncthreads();
#pragma unroll
    for (int kk = 0; kk < 2; ++kk) {
      bf16x8 af[4], bfr[2];
      const int sl = (((kk * 4 + quad) ^ (l16 & 7)) * 8);
#pragma unroll
      for (int mt = 0; mt < 4; ++mt)
        af[mt] = *(const bf16x8*)&lsA[(wr * 64 + mt * 16 + l16) * 64 + sl];
#pragma unroll
      for (int nt = 0; nt < 2; ++nt)
        bfr[nt] = *(const bf16x8*)&lsB[(wc * 32 + nt * 16 + l16) * 64 + sl];
#pragma unroll
      for (int mt = 0; mt < 4; ++mt)
#pragma unroll
        for (int nt = 0; nt < 2; ++nt)
          acc[mt][nt] = __builtin_amdgcn_mfma_f32_16x16x32_bf16(af[mt], bfr[nt], acc[mt][nt], 0, 0, 0);
    }
    __syncthreads();
  }

  const int rb = row0 + wr * 64;
  const int cb = col0 + wc * 32;
#pragma unroll
  for (int mt = 0; mt < 4; ++mt) {
#pragma unroll
    for (int nt = 0; nt < 2; ++nt) {
      const int r = rb + mt * 16 + quad * 4;
      const int c = cb + nt * 16 + l16;
#pragma unroll
      for (int i = 0; i < 4; ++i)
        out[(size_t)(r + i) * N + c] = acc[mt][nt][i] + res[(size_t)(r + i) * N + c];
    }
  }
}

// out = p0+p1+p2+res (fp32)
__global__ __launch_bounds__(256) void reduce_add4(
    const float* __restrict__ p0, const float* __restrict__ p1,
    const float* __restrict__ p2, const float* __restrict__ res,
    float* __restrict__ out) {
  const int i = (blockIdx.x * 256 + threadIdx.x) * 4;
  const f32x4 a = *(const f32x4*)&p0[i];
  const f32x4 b = *(const f32x4*)&p1[i];
  const f32x4 c = *(const f32x4*)&p2[i];
  const f32x4 e = *(const f32x4*)&res[i];
  f32x4 o;
#pragma unroll
  for (int k = 0; k < 4; ++k) o[k] = ((a[k] + b[k]) + c[k]) + e[k];
  *(f32x4*)&out[i] = o;
}

// ---------------------------------------------------------------------------
// LayerNorm over D=1024, one token per 256-thread block, bf16 out.
// ---------------------------------------------------------------------------
__global__ __launch_bounds__(256) void ln_kernel(
    const float* __restrict__ x, const float* __restrict__ g,
    const float* __restrict__ be, unsigned short* __restrict__ out) {
  __shared__ float sbuf[4];
  const int t = blockIdx.x, tid = threadIdx.x;
  const float* row = x + (size_t)t * 1024;
  float v[4], s = 0.f;
#pragma unroll
  for (int j = 0; j < 4; ++j) { v[j] = row[tid + j * 256]; s += v[j]; }
#pragma unroll
  for (int off = 32; off; off >>= 1) s += __shfl_xor(s, off);
  if ((tid & 63) == 0) sbuf[tid >> 6] = s;
  __syncthreads();
  const float mu = (sbuf[0] + sbuf[1] + sbuf[2] + sbuf[3]) * (1.f / 1024.f);
  __syncthreads();
  float ss = 0.f;
#pragma unroll
  for (int j = 0; j < 4; ++j) { const float d = v[j] - mu; ss += d * d; }
#pragma unroll
  for (int off = 32; off; off >>= 1) ss += __shfl_xor(ss, off);
  if ((tid & 63) == 0) sbuf[tid >> 6] = ss;
  __syncthreads();
  const float var = (sbuf[0] + sbuf[1] + sbuf[2] + sbuf[3]) * (1.f / 1024.f);
  const float rstd = rsqrtf(var + 1e-5f);
  unsigned short* orow = out + (size_t)t * 1024;
#pragma unroll
  for (int j = 0; j < 4; ++j) {
    const int c = tid + j * 256;
    orow[c] = f2b((v[j] - mu) * rstd * g[c] + be[c]);
  }
}

// ---------------------------------------------------------------------------
// Attention mixing. Phase-2 writes vectorized: uint4 (8 bf16) per store.
// ---------------------------------------------------------------------------
__global__ __launch_bounds__(256) void mix_attn(
    const unsigned short* __restrict__ all_h,
    const float* __restrict__ w_fq, const float* __restrict__ w_fk,
    const float* __restrict__ w_fv, const float* __restrict__ w_rq,
    const float* __restrict__ w_rk, const float* __restrict__ w_rv,
    unsigned short* __restrict__ t_qk, unsigned short* __restrict__ t_v) {
  __shared__ float hq[64], hk[64], hv[64];
  const int t = blockIdx.x, tid = threadIdx.x;
  const int wvi = tid >> 6, lane = tid & 63;
  const unsigned short* row = all_h + (size_t)t * 4096;
  if (wvi < 3) {
    const float* wf = (wvi == 0 ? w_fq : wvi == 1 ? w_fk : w_fv) + (size_t)t * 32;
    const int base = (wvi == 2) ? 2048 : 0;
    float acc = 0.f;
#pragma unroll
    for (int n = 0; n < 32; ++n) acc += wf[n] * b2f(row[base + n * 64 + lane]);
    (wvi == 0 ? hq : wvi == 1 ? hk : hv)[lane] = acc;
  }
  __syncthreads();
  const int n = tid >> 3, r0 = (tid & 7) * 8;
  const float wq = w_rq[(size_t)t * 32 + n];
  const float wk = w_rk[(size_t)t * 32 + n];
  const float wv2 = w_rv[(size_t)t * 32 + n];
  unsigned dq[4], dk[4], dv[4];
#pragma unroll
  for (int jj = 0; jj < 4; ++jj) {
    dq[jj] = pk2(wq * hq[r0 + 2 * jj], wq * hq[r0 + 2 * jj + 1]);
    dk[jj] = pk2(wk * hk[r0 + 2 * jj], wk * hk[r0 + 2 * jj + 1]);
    dv[jj] = pk2(wv2 * hv[r0 + 2 * jj], wv2 * hv[r0 + 2 * jj + 1]);
  }
  *(uint4*)&t_qk[(size_t)t * 2048 + tid * 8] = *(uint4*)dq;
  *(uint4*)&t_qk[(size_t)(4096 + t) * 2048 + tid * 8] = *(uint4*)dk;
  *(uint4*)&t_v[(size_t)t * 2048 + tid * 8] = *(uint4*)dv;
}

// Knowledge mixing (RK=128), vectorized stores
__global__ __launch_bounds__(256) void mix_know(
    const unsigned short* __restrict__ all_h, const float* __restrict__ w_f,
    const float* __restrict__ w_r, unsigned short* __restrict__ t_know) {
  __shared__ float h[128];
  const int t = blockIdx.x, tid = threadIdx.x;
  const unsigned short* row = all_h + (size_t)t * 4096;
  if (tid < 128) {
    const float* wf = w_f + (size_t)t * 32;
    float acc = 0.f;
#pragma unroll
    for (int n = 0; n < 32; ++n) acc += wf[n] * b2f(row[n * 128 + tid]);
    h[tid] = acc;
  }
  __syncthreads();
  const int n = tid >> 3, r0 = (tid & 7) * 16;
  const float wn = w_r[(size_t)t * 32 + n];
  unsigned d[8];
#pragma unroll
  for (int jj = 0; jj < 8; ++jj)
    d[jj] = pk2(wn * h[r0 + 2 * jj], wn * h[r0 + 2 * jj + 1]);
  *(uint4*)&t_know[(size_t)t * 4096 + tid * 16] = *(uint4*)d;
  *(uint4*)&t_know[(size_t)t * 4096 + tid * 16 + 8] = *(uint4*)&d[4];
}

// ---------------------------------------------------------------------------
// Merged weight prep: 6 transposes + W_O convert in ONE dispatch.
// ---------------------------------------------------------------------------
__global__ __launch_bounds__(256) void prep_all(
    const float* __restrict__ f_qk, const float* __restrict__ f_v,
    const float* __restrict__ f_know, const float* __restrict__ r_qk,
    const float* __restrict__ r_v, const float* __restrict__ r_know,
    const float* __restrict__ W_O,
    unsigned short* __restrict__ fcomb, unsigned short* __restrict__ fknowT,
    unsigned short* __restrict__ r_qkT, unsigned short* __restrict__ r_vT,
    unsigned short* __restrict__ r_knowT, unsigned short* __restrict__ WO_bf) {
  __shared__ float tile[32][33];
  const int bid = blockIdx.x;
  const int tx = threadIdx.x, ty = threadIdx.y;
  const float* in;
  unsigned short* out;
  int R, C, gx, loc;
  if (bid < 2048)       { in = f_qk;   out = fcomb;                         R = 1024; C = 64;   gx = 2;  loc = bid; }
  else if (bid < 4096)  { in = f_v;    out = fcomb + (size_t)2048 * 1024;   R = 1024; C = 64;   gx = 2;  loc = bid - 2048; }
  else if (bid < 8192)  { in = f_know; out = fknowT;                        R = 1024; C = 128;  gx = 4;  loc = bid - 4096; }
  else if (bid < 10240) { in = r_qk;   out = r_qkT;                         R = 2048; C = 1024; gx = 32; loc = bid - 8192; }
  else if (bid < 12288) { in = r_v;    out = r_vT;                          R = 2048; C = 1024; gx = 32; loc = bid - 10240; }
  else if (bid < 16384) { in = r_know; out = r_knowT;                       R = 4096; C = 1024; gx = 32; loc = bid - 12288; }
  else {
    const int i = ((bid - 16384) * 256 + ty * 32 + tx) * 4;
    const f32x4 v = *(const f32x4*)&W_O[i];
    *(unsigned*)&WO_bf[i] = pk2(v[0], v[1]);
    *(unsigned*)&WO_bf[i + 2] = pk2(v[2], v[3]);
    return;
  }
  const int tiles = gx * (R >> 5);
  const int bb = loc / tiles, rem = loc % tiles;
  const int r0 = (rem / gx) * 32, c0 = (rem % gx) * 32;
  const float* ip = in + (size_t)bb * R * C;
  unsigned short* op = out + (size_t)bb * R * C;
#pragma unroll
  for (int j = 0; j < 4; ++j)
    tile[ty + j * 8][tx] = ip[(size_t)(r0 + ty + j * 8) * C + c0 + tx];
  __syncthreads();
#pragma unroll
  for (int j = 0; j < 4; ++j)
    op[(size_t)(c0 + ty + j * 8) * R + r0 + tx] = f2b(tile[tx][ty + j * 8]);
}

// ---------------------------------------------------------------------------
// Causal flash attention: SPLIT-K over history, uniform work units.
// v9: branch-free fast path (diag tile handled once, outside the k-loop);
// f32x4 packed softmax math; LDS staging kept (dedups K/V requests 4x).
// ---------------------------------------------------------------------------
__global__ __launch_bounds__(256) void flash_split(
    const unsigned short* __restrict__ Q, const unsigned short* __restrict__ Kp,
    const unsigned short* __restrict__ VT, unsigned short* __restrict__ O,
    float* __restrict__ Opart, float* __restrict__ ml) {
  __shared__ unsigned short Kls[2][64 * 64];
  __shared__ unsigned short Vls[2][64 * 64];
  const int uidx = 79 - (int)blockIdx.x;
  int uu = uidx, qt = 0, ch = 0;
  for (int q = 0; q < 32; ++q) {
    const int n = (q >> 3) + 1;
    if (uu < n) { qt = q; ch = uu; break; }
    uu -= n;
  }
  const int bh = blockIdx.y;
  const int b = bh >> 4, h = bh & 15;
  const int tid = threadIdx.x;
  const int w = tid >> 6, lane = tid & 63, quad = lane >> 4, l16 = lane & 15;
  const int tb = b * 2048;
  const int qrow = qt * 64 + w * 16;
  const int ktlo = ch * 8;
  const int kthi = min(qt, ch * 8 + 7);
  const float C = 0.18033688f;  // (1/sqrt(64)) * log2(e)

  const int srow = (lane >> 3);
  const int scol = ((lane & 7) ^ srow) * 8;

  bf16x8 qf[2];
#pragma unroll
  for (int kk = 0; kk < 2; ++kk)
    qf[kk] = *(const bf16x8*)&Q[(size_t)(tb + qrow + l16) * 1024 + h * 64 + kk * 32 + quad * 8];

  const f32x4 fz = {0.f, 0.f, 0.f, 0.f};
  float m_i = -1e30f, l_i = 0.f;
  f32x4 o_acc[4];
#pragma unroll
  for (int nt = 0; nt < 4; ++nt) o_acc[nt] = fz;

  auto stage = [&](int buf, int kt) {
#pragma unroll
    for (int j = 0; j < 2; ++j) {
      const int rg = (w * 2 + j) * 8 + srow;
      __builtin_amdgcn_global_load_lds(
          (const __attribute__((address_space(1))) unsigned int*)
              (Kp + (size_t)(tb + kt * 64 + rg) * 1024 + h * 64 + scol),
          (__attribute__((address_space(3))) unsigned int*)&Kls[buf][(w * 2 + j) * 8 * 64],
          16, 0, 0);
      __builtin_amdgcn_global_load_lds(
          (const __attribute__((address_space(1))) unsigned int*)
              (VT + (size_t)(h * 64 + rg) * 4096 + tb + kt * 64 + scol),
          (__attribute__((address_space(3))) unsigned int*)&Vls[buf][(w * 2 + j) * 8 * 64],
          16, 0, 0);
    }
  };

  const int srcA = (((quad & 1) * 32 + l16) << 2);
  const int srcB = srcA + 64;
  const bool hiq = (quad >= 2);

  // pack P -> bf16, redistribute across quads, run PV MFMAs, fold l.
  auto pv_block = [&](f32x4* s, bf16x8* vf, const f32x4& rsv) {
    unsigned pk[4][2];
#pragma unroll
    for (int nt = 0; nt < 4; ++nt) {
      pk[nt][0] = pkt(s[nt][0], s[nt][1]);
      pk[nt][1] = pkt(s[nt][2], s[nt][3]);
    }
#pragma unroll
    for (int kk = 0; kk < 2; ++kk) {
      const int ea = 2 * kk, eb = 2 * kk + 1;
      const unsigned u0 = __builtin_amdgcn_ds_bpermute(srcA, pk[ea][0]);
      const unsigned u1 = __builtin_amdgcn_ds_bpermute(srcA, pk[ea][1]);
      const unsigned u2 = __builtin_amdgcn_ds_bpermute(srcB, pk[ea][0]);
      const unsigned u3 = __builtin_amdgcn_ds_bpermute(srcB, pk[ea][1]);
      const unsigned w0 = __builtin_amdgcn_ds_bpermute(srcA, pk[eb][0]);
      const unsigned w1 = __builtin_amdgcn_ds_bpermute(srcA, pk[eb][1]);
      const unsigned w2 = __builtin_amdgcn_ds_bpermute(srcB, pk[eb][0]);
      const unsigned w3 = __builtin_amdgcn_ds_bpermute(srcB, pk[eb][1]);
      unsigned dw[4];
      dw[0] = hiq ? w0 : u0;
      dw[1] = hiq ? w1 : u1;
      dw[2] = hiq ? w2 : u2;
      dw[3] = hiq ? w3 : u3;
      const bf16x8 pf = *(const bf16x8*)dw;
      __builtin_amdgcn_s_setprio(1);
#pragma unroll
      for (int nt = 0; nt < 4; ++nt)
        o_acc[nt] = __builtin_amdgcn_mfma_f32_16x16x32_bf16(vf[kk * 4 + nt], pf, o_acc[nt], 0, 0, 0);
      __builtin_amdgcn_s_setprio(0);
    }
    float rs = (rsv[0] + rsv[1]) + (rsv[2] + rsv[3]);
    rs += __shfl_xor(rs, 16);
    rs += __shfl_xor(rs, 32);
    l_i += rs;
  };

  stage(0, ktlo);
  __syncthreads();
  int buf = 0;

  const bool hasdiag = (ch == (qt >> 3));
  const int ktnd = hasdiag ? kthi - 1 : kthi;  // last non-diag tile

  // ---- fast path: branch-free, no masking ----
  for (int kt = ktlo; kt <= ktnd; ++kt) {
    if (kt < kthi) stage(buf ^ 1, kt + 1);
    bf16x8 kf[8], vf[8];
#pragma unroll
    for (int kk = 0; kk < 2; ++kk)
#pragma unroll
      for (int nt = 0; nt < 4; ++nt) {
        const int sl = (((kk * 4 + quad) ^ (l16 & 7)) * 8);
        kf[kk * 4 + nt] = *(const bf16x8*)&Kls[buf][(nt * 16 + l16) * 64 + sl];
        vf[kk * 4 + nt] = *(const bf16x8*)&Vls[buf][(nt * 16 + l16) * 64 + sl];
      }

    f32x4 s[4];
    __builtin_amdgcn_s_setprio(1);
#pragma unroll
    for (int nt = 0; nt < 4; ++nt)
      s[nt] = __builtin_amdgcn_mfma_f32_16x16x32_bf16(kf[nt], qf[0], fz, 0, 0, 0);
#pragma unroll
    for (int nt = 0; nt < 4; ++nt)
      s[nt] = __builtin_amdgcn_mfma_f32_16x16x32_bf16(kf[4 + nt], qf[1], s[nt], 0, 0, 0);
    __builtin_amdgcn_s_setprio(0);

    const f32x4 m4 = vmax4(vmax4(s[0], s[1]), vmax4(s[2], s[3]));
    float mx = fmaxf(fmaxf(m4[0], m4[1]), fmaxf(m4[2], m4[3]));
    mx = fmaxf(mx, __shfl_xor(mx, 16));
    mx = fmaxf(mx, __shfl_xor(mx, 32));
    if (!__all(mx <= m_i)) {
      const float mn = fmaxf(m_i, mx);
      const float al = exp2f((m_i - mn) * C);
      m_i = mn;
      l_i *= al;
#pragma unroll
      for (int nt = 0; nt < 4; ++nt) o_acc[nt] *= al;
    }
    const float mC = m_i * C;
    f32x4 rsv = fz;
#pragma unroll
    for (int nt = 0; nt < 4; ++nt) {
      f32x4 e = s[nt] * C - mC;  // v_pk_fma_f32 x2
      f32x4 p;
#pragma unroll
      for (int i = 0; i < 4; ++i) p[i] = exp2f(e[i]);
      s[nt] = p;
      rsv += p;                  // v_pk_add_f32 x2
    }
    pv_block(s, vf, rsv);
    __syncthreads();
    buf ^= 1;
  }

  // ---- diagonal tile (at most once per block) ----
  if (hasdiag) {
    bf16x8 kf[8], vf[8];
#pragma unroll
    for (int kk = 0; kk < 2; ++kk)
#pragma unroll
      for (int nt = 0; nt < 4; ++nt) {
        const int sl = (((kk * 4 + quad) ^ (l16 & 7)) * 8);
        kf[kk * 4 + nt] = *(const bf16x8*)&Kls[buf][(nt * 16 + l16) * 64 + sl];
        vf[kk * 4 + nt] = *(const bf16x8*)&Vls[buf][(nt * 16 + l16) * 64 + sl];
      }
    const int ntmax = w + 1;  // wave-uniform live nt count
    f32x4 s[4];
#pragma unroll
    for (int nt = 0; nt < 4; ++nt) s[nt] = fz;
    __builtin_amdgcn_s_setprio(1);
#pragma unroll
    for (int kk = 0; kk < 2; ++kk)
#pragma unroll
      for (int nt = 0; nt < 4; ++nt)
        if (nt < ntmax)
          s[nt] = __builtin_amdgcn_mfma_f32_16x16x32_bf16(kf[kk * 4 + nt], qf[kk], s[nt], 0, 0, 0);
    __builtin_amdgcn_s_setprio(0);

    const int qloc = w * 16 + l16;
    float mxs[4] = {-1e30f, -1e30f, -1e30f, -1e30f};
#pragma unroll
    for (int nt = 0; nt < 4; ++nt) {
      if (nt >= ntmax) continue;
#pragma unroll
      for (int i = 0; i < 4; ++i) {
        float v = s[nt][i];
        if ((nt * 16 + quad * 4 + i) > qloc) v = -1e30f;
        s[nt][i] = v;
        mxs[nt] = fmaxf(mxs[nt], v);
      }
    }
    float mx = fmaxf(fmaxf(mxs[0], mxs[1]), fmaxf(mxs[2], mxs[3]));
    mx = fmaxf(mx, __shfl_xor(mx, 16));
    mx = fmaxf(mx, __shfl_xor(mx, 32));
    if (!__all(mx <= m_i)) {
      const float mn = fmaxf(m_i, mx);
      const float al = exp2f((m_i - mn) * C);
      m_i = mn;
      l_i *= al;
#pragma unroll
      for (int nt = 0; nt < 4; ++nt) o_acc[nt] *= al;
    }
    const float mC = m_i * C;
    f32x4 rsv = fz;
#pragma unroll
    for (int nt = 0; nt < 4; ++nt) {
      if (nt >= ntmax) { s[nt] = fz; continue; }
      f32x4 e = s[nt] * C - mC;
      f32x4 p;
#pragma unroll
      for (int i = 0; i < 4; ++i) p[i] = exp2f(e[i]);
      s[nt] = p;
      rsv += p;
    }
    pv_block(s, vf, rsv);
  }

  const int nch = (qt >> 3) + 1;
  if (nch == 1) {
    const float inv = 1.0f / l_i;
    unsigned short* orow = O + (size_t)(tb + qrow + l16) * 1024 + h * 64;
#pragma unroll
    for (int nt = 0; nt < 4; ++nt) {
      const unsigned d0 = pk2(o_acc[nt][0] * inv, o_acc[nt][1] * inv);
      const unsigned d1 = pk2(o_acc[nt][2] * inv, o_acc[nt][3] * inv);
      *(unsigned*)&orow[nt * 16 + quad * 4] = d0;
      *(unsigned*)&orow[nt * 16 + quad * 4 + 2] = d1;
    }
  } else {
    const int slot = bh * 80 + uidx;
    const int lq = w * 16 + l16;
    float* op = Opart + ((size_t)slot * 64 + lq) * 64;
#pragma unroll
    for (int nt = 0; nt < 4; ++nt)
      *(f32x4*)&op[nt * 16 + quad * 4] = o_acc[nt];
    if (quad == 0) {
      ml[(size_t)slot * 128 + lq * 2] = m_i;
      ml[(size_t)slot * 128 + lq * 2 + 1] = l_i;
    }
  }
}

// ---------------------------------------------------------------------------
// Combine flash split-K partials for qt in [8,31]. Grid (24, 32).
// ---------------------------------------------------------------------------
__global__ __launch_bounds__(256) void flash_reduce(
    const float* __restrict__ Opart, const float* __restrict__ ml,
    unsigned short* __restrict__ O) {
  const int qt = 8 + blockIdx.x;
  const int bh = blockIdx.y;
  const int b = bh >> 4, h = bh & 15;
  const int j = qt >> 3;
  const int base = 8 * (j * (j + 1) / 2) + (qt - 8 * j) * (j + 1);
  const int nch = j + 1;
  const int tid = threadIdx.x;
  const int lq = tid >> 2, dq = (tid & 3) * 16;
  const float C = 0.18033688f;

  float mc[4], lc[4];
  float m = -1e30f;
#pragma unroll
  for (int c = 0; c < 4; ++c) {
    if (c < nch) {
      const size_t sl = (size_t)(bh * 80 + base + c) * 128 + lq * 2;
      mc[c] = ml[sl];
      lc[c] = ml[sl + 1];
    } else { mc[c] = -1e30f; lc[c] = 0.f; }
    m = fmaxf(m, mc[c]);
  }
  float fac[4], lt = 0.f;
#pragma unroll
  for (int c = 0; c < 4; ++c) {
    fac[c] = (c < nch) ? exp2f((mc[c] - m) * C) : 0.f;
    lt += fac[c] * lc[c];
  }
  const float inv = 1.0f / lt;
  float acc[16];
#pragma unroll
  for (int i = 0; i < 16; ++i) acc[i] = 0.f;
#pragma unroll
  for (int c = 0; c < 4; ++c) {
    if (c >= nch) continue;
    const float* op = Opart + ((size_t)(bh * 80 + base + c) * 64 + lq) * 64 + dq;
#pragma unroll
    for (int i = 0; i < 16; i += 4) {
      const f32x4 v = *(const f32x4*)&op[i];
#pragma unroll
      for (int k = 0; k < 4; ++k) acc[i + k] += fac[c] * v[k];
    }
  }
  unsigned short* orow = O + (size_t)(b * 2048 + qt * 64 + lq) * 1024 + h * 64 + dq;
#pragma unroll
  for (int i = 0; i < 16; i += 2)
    *(unsigned*)&orow[i] = pk2(acc[i] * inv, acc[i + 1] * inv);
}

// ---------------------------------------------------------------------------
extern "C" void kernel_launch(void* const* d_in, const int* in_sizes, int n_in,
                              void* d_out, int out_size, void* d_ws, size_t ws_size,
                              hipStream_t stream) {
  (void)in_sizes; (void)n_in; (void)out_size; (void)ws_size;
  const float* x      = (const float*)d_in[0];
  const float* f_qk   = (const float*)d_in[1];
  const float* f_v    = (const float*)d_in[2];
  const float* r_qk   = (const float*)d_in[3];
  const float* r_v    = (const float*)d_in[4];
  const float* f_know = (const float*)d_in[5];
  const float* r_know = (const float*)d_in[6];
  const float* W_O    = (const float*)d_in[7];
  const float* gamma1 = (const float*)d_in[8];
  const float* beta1  = (const float*)d_in[9];
  const float* gamma2 = (const float*)d_in[10];
  const float* beta2  = (const float*)d_in[11];
  const float* w_fq   = (const float*)d_in[12];
  const float* w_fk   = (const float*)d_in[13];
  const float* w_fv   = (const float*)d_in[14];
  const float* w_rq   = (const float*)d_in[15];
  const float* w_rk   = (const float*)d_in[16];
  const float* w_rv   = (const float*)d_in[17];
  const float* w_kf   = (const float*)d_in[18];
  const float* w_kr   = (const float*)d_in[19];

  char* base = (char*)d_ws;
  size_t off = 0;
  auto alloc = [&](size_t b) { char* p = base + off; off += (b + 255) & ~(size_t)255; return p; };
  unsigned short* fcomb   = (unsigned short*)alloc(8388608);   // [4096][1024]
  unsigned short* fknowT  = (unsigned short*)alloc(8388608);   // [4096][1024]
  unsigned short* r_qkT   = (unsigned short*)alloc(4194304);   // [1024][2048]
  unsigned short* r_vT    = (unsigned short*)alloc(4194304);   // [1024][2048]
  unsigned short* r_knowT = (unsigned short*)alloc(8388608);   // [1024][4096]
  unsigned short* WO_bf   = (unsigned short*)alloc(2097152);   // [1024][1024]
  unsigned short* nx_bf   = (unsigned short*)alloc(8388608);   // [4096][1024]
  unsigned short* all_h   = (unsigned short*)alloc(33554432);  // [4096][4096]
  unsigned short* t_qk    = (unsigned short*)alloc(33554432);  // [8192][2048]
  unsigned short* t_v     = (unsigned short*)alloc(16777216);  // [4096][2048]; reused as x1 fp32
  unsigned short* QKbuf   = (unsigned short*)alloc(16777216);  // [8192][1024]
  unsigned short* VT      = (unsigned short*)alloc(8388608);   // [1024][4096]
  unsigned short* attn    = (unsigned short*)alloc(8388608);   // [4096][1024]
  float* x1 = (float*)t_v;                    // t_v dead before x1 written
  float* Opart = (float*)all_h;               // flash partials (spills into t_qk, dead)
  float* mlbuf = (float*)((char*)all_h + 41943040);
  float* pW0 = (float*)all_h;                 // ks3 fp32 partials (knowledge)
  float* pW1 = (float*)((char*)all_h + 16777216);
  float* pW2 = (float*)QKbuf;

  const dim3 blk256(256), blk512(512), blkT(32, 8);

  prep_all<<<17408, blkT, 0, stream>>>(f_qk, f_v, f_know, r_qk, r_v, r_know, W_O,
                                       fcomb, fknowT, r_qkT, r_vT, r_knowT, WO_bf);

  // attention circuit
  ln_kernel<<<4096, blk256, 0, stream>>>(x, gamma1, beta1, nx_bf);
  gemm_bt256<<<256, blk512, 0, stream>>>(nx_bf, fcomb, all_h, 1024);
  mix_attn<<<4096, blk256, 0, stream>>>(all_h, w_fq, w_fk, w_fv, w_rq, w_rk, w_rv, t_qk, t_v);
  gemm_qkv<<<768, blk256, 0, stream>>>(t_qk, t_v, r_qkT, r_vT, QKbuf, VT);
  flash_split<<<dim3(80, 32), blk256, 0, stream>>>(QKbuf, QKbuf + (size_t)4096 * 1024, VT, attn,
                                                   Opart, mlbuf);
  flash_reduce<<<dim3(24, 32), blk256, 0, stream>>>(Opart, mlbuf, attn);
  gemm_wo_res<<<512, blk256, 0, stream>>>(attn, WO_bf, x, x1);

  // knowledge circuit
  ln_kernel<<<4096, blk256, 0, stream>>>(x1, gamma2, beta2, nx_bf);
  gemm_bt256<<<256, blk512, 0, stream>>>(nx_bf, fknowT, all_h, 1024);
  mix_know<<<4096, blk256, 0, stream>>>(all_h, w_kf, w_kr, t_qk);
  gemm_ks3<<<768, blk256, 0, stream>>>(t_qk, r_knowT, pW0, pW1, pW2);
  reduce_add4<<<4096, blk256, 0, stream>>>(pW0, pW1, pW2, x1, (float*)d_out);
}

// Round 10
// 466.824 us; speedup vs baseline: 1.0390x; 1.0390x over previous
//
#include <hip/hip_runtime.h>
#include <stdint.h>

// B=2,S=2048,D=1024,H=16,R=64,N=32,RK=128,DH=64. Tokens T=4096.

typedef __bf16 bf16x8 __attribute__((ext_vector_type(8)));
typedef float f32x4 __attribute__((ext_vector_type(4)));

__device__ __forceinline__ unsigned short f2b(float f) {
  union { float f; unsigned u; } v; v.f = f;
  unsigned u = v.u;
  unsigned r = (u + 0x7FFFu + ((u >> 16) & 1u)) >> 16;  // RNE
  return (unsigned short)r;
}
__device__ __forceinline__ float b2f(unsigned short h) {
  union { unsigned u; float f; } v; v.u = ((unsigned)h) << 16;
  return v.f;
}
__device__ __forceinline__ unsigned pk2(float lo, float hi) {
  return (unsigned)f2b(lo) | ((unsigned)f2b(hi) << 16);
}
// truncation pack: one v_perm_b32 (bytes: [hi.b3, hi.b2, lo.b3, lo.b2])
__device__ __forceinline__ unsigned pkt(float lo, float hi) {
  union { float f; unsigned u; } a, b; a.f = lo; b.f = hi;
  return __builtin_amdgcn_perm(b.u, a.u, 0x07060302u);
}
__device__ __forceinline__ f32x4 vmax4(f32x4 a, f32x4 b) {
  f32x4 r;
  r[0] = fmaxf(a[0], b[0]); r[1] = fmaxf(a[1], b[1]);
  r[2] = fmaxf(a[2], b[2]); r[3] = fmaxf(a[3], b[3]);
  return r;
}

// ---------------------------------------------------------------------------
// 256x256-tile bf16 GEMM, BK=64, 8 waves (512 thr), double-buffered LDS
// (128 KiB), counted-vmcnt schedule (raw s_barrier; never drain to 0 in the
// main loop). C[M,N] = A[M,K] @ Bt[N,K]^T, M=N=4096. 256 blocks = 1/CU.
// FIFO issue order per tile: A0,A2,B0,B1 | B2,B3,A1,A3 (64-row half-bands).
// Boundary wait vmcnt(2) -> A0,A2,B0..B3 landed; mid wait vmcnt(4) -> A1,A3.
// [R9 lesson: finer 8-phase split regressed (+5us/call) at 1 block/CU and
//  K=1024 — barrier overhead not amortized; coarse schedule is the winner.]
// ---------------------------------------------------------------------------
#define PHASE(M0) { \
  const bf16x8 a00 = *(const bf16x8*)&lsA[cur][(wr * 128 + (M0) * 16 + l16) * 64 + sl0]; \
  const bf16x8 a01 = *(const bf16x8*)&lsA[cur][(wr * 128 + (M0) * 16 + l16) * 64 + sl1]; \
  const bf16x8 a10 = *(const bf16x8*)&lsA[cur][(wr * 128 + (M0 + 1) * 16 + l16) * 64 + sl0]; \
  const bf16x8 a11 = *(const bf16x8*)&lsA[cur][(wr * 128 + (M0 + 1) * 16 + l16) * 64 + sl1]; \
  __builtin_amdgcn_s_setprio(1); \
  _Pragma("unroll") \
  for (int n = 0; n < 4; ++n) { \
    acc[M0][n] = __builtin_amdgcn_mfma_f32_16x16x32_bf16(a00, bfr[n][0], acc[M0][n], 0, 0, 0); \
    acc[M0][n] = __builtin_amdgcn_mfma_f32_16x16x32_bf16(a01, bfr[n][1], acc[M0][n], 0, 0, 0); \
    acc[M0 + 1][n] = __builtin_amdgcn_mfma_f32_16x16x32_bf16(a10, bfr[n][0], acc[M0 + 1][n], 0, 0, 0); \
    acc[M0 + 1][n] = __builtin_amdgcn_mfma_f32_16x16x32_bf16(a11, bfr[n][1], acc[M0 + 1][n], 0, 0, 0); \
  } \
  __builtin_amdgcn_s_setprio(0); }

__global__ __launch_bounds__(512, 2) void gemm_bt256(
    const unsigned short* __restrict__ A, const unsigned short* __restrict__ Bt,
    unsigned short* __restrict__ out, int K) {
  __shared__ unsigned short lsA[2][256 * 64];
  __shared__ unsigned short lsB[2][256 * 64];
  const int N = 4096;
  const int bid = blockIdx.x;
  const int xcd = bid & 7, j = bid >> 3;
  const int row0 = (xcd * 2 + (j >> 4)) * 256;
  const int col0 = (j & 15) * 256;
  const int tid = threadIdx.x;
  const int w = tid >> 6, lane = tid & 63;
  const int quad = lane >> 4, l16 = lane & 15;
  const int wr = w >> 2, wc = w & 3;

  const int scg = ((lane & 7) ^ (lane >> 3)) * 8;
  const unsigned short* apg = A + (size_t)(row0 + w * 8 + (lane >> 3)) * K + scg;
  const unsigned short* bpg = Bt + (size_t)(col0 + w * 8 + (lane >> 3)) * K + scg;

  const int sl0 = (quad ^ (l16 & 7)) * 8;
  const int sl1 = ((4 + quad) ^ (l16 & 7)) * 8;

  const f32x4 fz = {0.f, 0.f, 0.f, 0.f};
  f32x4 acc[8][4];
#pragma unroll
  for (int m = 0; m < 8; ++m)
#pragma unroll
    for (int n = 0; n < 4; ++n) acc[m][n] = fz;

  auto stA = [&](int b, int i, int k0) {
    __builtin_amdgcn_global_load_lds(
        (const __attribute__((address_space(1))) unsigned int*)(apg + (size_t)(i * 64) * K + k0),
        (__attribute__((address_space(3))) unsigned int*)&lsA[b][(i * 64 + w * 8) * 64],
        16, 0, 0);
  };
  auto stB = [&](int b, int i, int k0) {
    __builtin_amdgcn_global_load_lds(
        (const __attribute__((address_space(1))) unsigned int*)(bpg + (size_t)(i * 64) * K + k0),
        (__attribute__((address_space(3))) unsigned int*)&lsB[b][(i * 64 + w * 8) * 64],
        16, 0, 0);
  };

  const int T = K >> 6;
  // prologue: tile 0, FIFO order A0,A2,B0,B1,B2,B3,A1,A3  (8 outstanding)
  stA(0, 0, 0); stA(0, 2, 0);
  stB(0, 0, 0); stB(0, 1, 0); stB(0, 2, 0); stB(0, 3, 0);
  stA(0, 1, 0); stA(0, 3, 0);

  for (int t = 0; t < T; ++t) {
    const int cur = t & 1, nxt = cur ^ 1;
    const int k1 = (t + 1) << 6;
    const bool pf = (t + 1 < T);
    // boundary: first 6 loads of tile t (A0,A2,B0..B3) landed; A1,A3 may fly
    asm volatile("s_waitcnt vmcnt(2)" ::: "memory");
    __builtin_amdgcn_s_barrier();
    if (pf) { stA(nxt, 0, k1); stA(nxt, 2, k1); }
    bf16x8 bfr[4][2];
#pragma unroll
    for (int n = 0; n < 4; ++n) {
      bfr[n][0] = *(const bf16x8*)&lsB[cur][(wc * 64 + n * 16 + l16) * 64 + sl0];
      bfr[n][1] = *(const bf16x8*)&lsB[cur][(wc * 64 + n * 16 + l16) * 64 + sl1];
    }
    PHASE(0)
    if (pf) { stB(nxt, 0, k1); stB(nxt, 1, k1); }
    PHASE(2)
    // mid: A1,A3 of tile t landed (4 next-tile loads remain in flight)
    if (pf) { asm volatile("s_waitcnt vmcnt(4)" ::: "memory"); }
    else    { asm volatile("s_waitcnt vmcnt(0)" ::: "memory"); }
    __builtin_amdgcn_s_barrier();
    if (pf) { stB(nxt, 2, k1); stB(nxt, 3, k1); }
    PHASE(4)
    if (pf) { stA(nxt, 1, k1); stA(nxt, 3, k1); }
    PHASE(6)
  }

  const int rb = row0 + wr * 128;
  const int cb = col0 + wc * 64;
#pragma unroll
  for (int m = 0; m < 8; ++m) {
#pragma unroll
    for (int n = 0; n < 4; ++n) {
      const int r = rb + m * 16 + quad * 4;
      const int c = cb + n * 16 + l16;
#pragma unroll
      for (int i = 0; i < 4; ++i)
        out[(size_t)(r + i) * N + c] = f2b(acc[m][n][i]);
    }
  }
}

// ---------------------------------------------------------------------------
// Fused Q/K (full-K, direct write) + V restore GEMM. 768 blocks, uniform work.
// fp32 accumulation end-to-end. 768 = 3 blocks/CU exactly with (256,3).
// ---------------------------------------------------------------------------
__global__ __launch_bounds__(256, 3) void gemm_qkv(
    const unsigned short* __restrict__ t_qk, const unsigned short* __restrict__ t_v,
    const unsigned short* __restrict__ r_qkT, const unsigned short* __restrict__ r_vT,
    unsigned short* __restrict__ QK, unsigned short* __restrict__ VT) {
  __shared__ unsigned short lsA[128 * 64];
  __shared__ unsigned short lsB[128 * 64];
  const int K = 2048;
  const int bid = blockIdx.x;
  const unsigned short* A;
  const unsigned short* Bt;
  int row0, col0, isv;
  if (bid < 256) {  // V restore: [4096,2048]@[1024,2048]^T -> VT (transposed)
    const int xcd = bid & 7, j = bid >> 3;
    row0 = (xcd * 4 + (j >> 3)) * 128;
    col0 = (j & 7) * 128;
    A = t_v; Bt = r_vT; isv = 1;
  } else {          // QK: [8192,2048]@[1024,2048]^T -> QKbuf direct
    const int u = bid - 256;
    const int xcd = u & 7, j = u >> 3;
    row0 = (xcd * 8 + (j >> 3)) * 128;
    col0 = (j & 7) * 128;
    A = t_qk; Bt = r_qkT; isv = 0;
  }
  const int tid = threadIdx.x;
  const int w = tid >> 6, lane = tid & 63;
  const int quad = lane >> 4, l16 = lane & 15;
  const int wr = w >> 1, wc = w & 1;

  const int srow = w * 32 + (lane >> 3);
  const int scg = ((lane & 7) ^ (lane >> 3)) * 8;
  const unsigned short* ap = A + (size_t)(row0 + srow) * K + scg;
  const unsigned short* bp = Bt + (size_t)(col0 + srow) * K + scg;

  const f32x4 fz = {0.f, 0.f, 0.f, 0.f};
  f32x4 acc[4][4];
#pragma unroll
  for (int i = 0; i < 4; ++i)
#pragma unroll
    for (int jj = 0; jj < 4; ++jj) acc[i][jj] = fz;

  for (int k0 = 0; k0 < K; k0 += 64) {
#pragma unroll
    for (int i = 0; i < 4; ++i) {
      __builtin_amdgcn_global_load_lds(
          (const __attribute__((address_space(1))) unsigned int*)(ap + (size_t)i * 8 * K + k0),
          (__attribute__((address_space(3))) unsigned int*)&lsA[(w * 32 + i * 8) * 64],
          16, 0, 0);
      __builtin_amdgcn_global_load_lds(
          (const __attribute__((address_space(1))) unsigned int*)(bp + (size_t)i * 8 * K + k0),
          (__attribute__((address_space(3))) unsigned int*)&lsB[(w * 32 + i * 8) * 64],
          16, 0, 0);
    }
    __syncthreads();
#pragma unroll
    for (int kk = 0; kk < 2; ++kk) {
      bf16x8 af[4], bfr[4];
      const int sl = (((kk * 4 + quad) ^ (l16 & 7)) * 8);
#pragma unroll
      for (int mt = 0; mt < 4; ++mt)
        af[mt] = *(const bf16x8*)&lsA[(wr * 64 + mt * 16 + l16) * 64 + sl];
#pragma unroll
      for (int nt = 0; nt < 4; ++nt)
        bfr[nt] = *(const bf16x8*)&lsB[(wc * 64 + nt * 16 + l16) * 64 + sl];
#pragma unroll
      for (int mt = 0; mt < 4; ++mt)
#pragma unroll
        for (int nt = 0; nt < 4; ++nt)
          acc[mt][nt] = __builtin_amdgcn_mfma_f32_16x16x32_bf16(af[mt], bfr[nt], acc[mt][nt], 0, 0, 0);
    }
    __syncthreads();
  }

  const int rb = row0 + wr * 64;
  const int cb = col0 + wc * 64;
#pragma unroll
  for (int mt = 0; mt < 4; ++mt) {
#pragma unroll
    for (int nt = 0; nt < 4; ++nt) {
      const int r = rb + mt * 16 + quad * 4;
      const int c = cb + nt * 16 + l16;
#pragma unroll
      for (int i = 0; i < 4; ++i) {
        const float v = acc[mt][nt][i];
        if (isv) VT[(size_t)c * 4096 + (r + i)] = f2b(v);
        else QK[(size_t)(r + i) * 1024 + c] = f2b(v);
      }
    }
  }
}

// ---------------------------------------------------------------------------
// Split-K x3 GEMM -> fp32 partials. M=4096, N=1024, K=4096 fixed.
// 768 blocks = 32 rows x 8 cols x 3 ks, XCD-banded -> exactly 3 blocks/CU,
// one packed round. K chunks 1344/1344/1408.
// ---------------------------------------------------------------------------
__global__ __launch_bounds__(256, 3) void gemm_ks3(
    const unsigned short* __restrict__ A, const unsigned short* __restrict__ Bt,
    float* __restrict__ p0, float* __restrict__ p1, float* __restrict__ p2) {
  __shared__ unsigned short lsA[128 * 64];
  __shared__ unsigned short lsB[128 * 64];
  const int N = 1024, K = 4096;
  const int bid = blockIdx.x;
  const int xcd = bid & 7, j = bid >> 3;          // j in [0,96)
  const int row_l = j / 24, rem = j % 24;          // 4 rows per xcd
  const int ks = rem >> 3, col = rem & 7;          // 3 ks x 8 cols
  const int row0 = (xcd * 4 + row_l) * 128;
  const int col0 = col * 128;
  const int kbeg = (ks == 0) ? 0 : (ks == 1) ? 1344 : 2688;
  const int kend = (ks == 0) ? 1344 : (ks == 1) ? 2688 : 4096;
  const int tid = threadIdx.x;
  const int w = tid >> 6, lane = tid & 63;
  const int quad = lane >> 4, l16 = lane & 15;
  const int wr = w >> 1, wc = w & 1;

  const int srow = w * 32 + (lane >> 3);
  const int scg = ((lane & 7) ^ (lane >> 3)) * 8;
  const unsigned short* ap = A + (size_t)(row0 + srow) * K + scg;
  const unsigned short* bp = Bt + (size_t)(col0 + srow) * K + scg;

  const f32x4 fz = {0.f, 0.f, 0.f, 0.f};
  f32x4 acc[4][4];
#pragma unroll
  for (int i = 0; i < 4; ++i)
#pragma unroll
    for (int jj = 0; jj < 4; ++jj) acc[i][jj] = fz;

  for (int k0 = kbeg; k0 < kend; k0 += 64) {
#pragma unroll
    for (int i = 0; i < 4; ++i) {
      __builtin_amdgcn_global_load_lds(
          (const __attribute__((address_space(1))) unsigned int*)(ap + (size_t)i * 8 * K + k0),
          (__attribute__((address_space(3))) unsigned int*)&lsA[(w * 32 + i * 8) * 64],
          16, 0, 0);
      __builtin_amdgcn_global_load_lds(
          (const __attribute__((address_space(1))) unsigned int*)(bp + (size_t)i * 8 * K + k0),
          (__attribute__((address_space(3))) unsigned int*)&lsB[(w * 32 + i * 8) * 64],
          16, 0, 0);
    }
    __syncthreads();
#pragma unroll
    for (int kk = 0; kk < 2; ++kk) {
      bf16x8 af[4], bfr[4];
      const int sl = (((kk * 4 + quad) ^ (l16 & 7)) * 8);
#pragma unroll
      for (int mt = 0; mt < 4; ++mt)
        af[mt] = *(const bf16x8*)&lsA[(wr * 64 + mt * 16 + l16) * 64 + sl];
#pragma unroll
      for (int nt = 0; nt < 4; ++nt)
        bfr[nt] = *(const bf16x8*)&lsB[(wc * 64 + nt * 16 + l16) * 64 + sl];
#pragma unroll
      for (int mt = 0; mt < 4; ++mt)
#pragma unroll
        for (int nt = 0; nt < 4; ++nt)
          acc[mt][nt] = __builtin_amdgcn_mfma_f32_16x16x32_bf16(af[mt], bfr[nt], acc[mt][nt], 0, 0, 0);
    }
    __syncthreads();
  }

  float* out = (ks == 0) ? p0 : (ks == 1) ? p1 : p2;
  const int rb = row0 + wr * 64;
  const int cb = col0 + wc * 64;
#pragma unroll
  for (int mt = 0; mt < 4; ++mt) {
#pragma unroll
    for (int nt = 0; nt < 4; ++nt) {
      const int r = rb + mt * 16 + quad * 4;
      const int c = cb + nt * 16 + l16;
#pragma unroll
      for (int i = 0; i < 4; ++i)
        out[(size_t)(r + i) * N + c] = acc[mt][nt][i];
    }
  }
}

// ---------------------------------------------------------------------------
// W_O GEMM with fused residual: x1 = attn @ WO^T + x. 128x64 tiles, no split-K.
// M=4096, N=1024, K=1024 -> 512 blocks (2/CU), fp32 out.
// ---------------------------------------------------------------------------
__global__ __launch_bounds__(256) void gemm_wo_res(
    const unsigned short* __restrict__ A, const unsigned short* __restrict__ Bt,
    const float* __restrict__ res, float* __restrict__ out) {
  __shared__ unsigned short lsA[128 * 64];
  __shared__ unsigned short lsB[64 * 64];
  const int K = 1024, N = 1024;
  const int bid = blockIdx.x;
  const int xcd = bid & 7, j = bid >> 3;
  const int row0 = (xcd * 4 + (j & 3)) * 128;   // 32 row-blocks
  const int col0 = (j >> 2) * 64;               // 16 col-blocks
  const int tid = threadIdx.x;
  const int w = tid >> 6, lane = tid & 63;
  const int quad = lane >> 4, l16 = lane & 15;
  const int wr = w >> 1, wc = w & 1;

  const int srowA = w * 32 + (lane >> 3);
  const int srowB = w * 16 + (lane >> 3);
  const int scg = ((lane & 7) ^ (lane >> 3)) * 8;
  const unsigned short* ap = A + (size_t)(row0 + srowA) * K + scg;
  const unsigned short* bp = Bt + (size_t)(col0 + srowB) * K + scg;

  const f32x4 fz = {0.f, 0.f, 0.f, 0.f};
  f32x4 acc[4][2];
#pragma unroll
  for (int i = 0; i < 4; ++i)
#pragma unroll
    for (int jj = 0; jj < 2; ++jj) acc[i][jj] = fz;

  for (int k0 = 0; k0 < K; k0 += 64) {
#pragma unroll
    for (int i = 0; i < 4; ++i)
      __builtin_amdgcn_global_load_lds(
          (const __attribute__((address_space(1))) unsigned int*)(ap + (size_t)i * 8 * K + k0),
          (__attribute__((address_space(3))) unsigned int*)&lsA[(w * 32 + i * 8) * 64],
          16, 0, 0);
#pragma unroll
    for (int i = 0; i < 2; ++i)
      __builtin_amdgcn_global_load_lds(
          (const __attribute__((address_space(1))) unsigned int*)(bp + (size_t)i * 8 * K + k0),
          (__attribute__((address_space(3))) unsigned int*)&lsB[(w * 16 + i * 8) * 64],
          16, 0, 0);
    __syncthreads();
#pragma unroll
    for (int kk = 0; kk < 2; ++kk) {
      bf16x8 af[4], bfr[2];
      const int sl = (((kk * 4 + quad) ^ (l16 & 7)) * 8);
#pragma unroll
      for (int mt = 0; mt < 4; ++mt)
        af[mt] = *(const bf16x8*)&lsA[(wr * 64 + mt * 16 + l16) * 64 + sl];
#pragma unroll
      for (int nt = 0; nt < 2; ++nt)
        bfr[nt] = *(const bf16x8*)&lsB[(wc * 32 + nt * 16 + l16) * 64 + sl];
#pragma unroll
      for (int mt = 0; mt < 4; ++mt)
#pragma unroll
        for (int nt = 0; nt < 2; ++nt)
          acc[mt][nt] = __builtin_amdgcn_mfma_f32_16x16x32_bf16(af[mt], bfr[nt], acc[mt][nt], 0, 0, 0);
    }
    __syncthreads();
  }

  const int rb = row0 + wr * 64;
  const int cb = col0 + wc * 32;
#pragma unroll
  for (int mt = 0; mt < 4; ++mt) {
#pragma unroll
    for (int nt = 0; nt < 2; ++nt) {
      const int r = rb + mt * 16 + quad * 4;
      const int c = cb + nt * 16 + l16;
#pragma unroll
      for (int i = 0; i < 4; ++i)
        out[(size_t)(r + i) * N + c] = acc[mt][nt][i] + res[(size_t)(r + i) * N + c];
    }
  }
}

// out = p0+p1+p2+res (fp32)
__global__ __launch_bounds__(256) void reduce_add4(
    const float* __restrict__ p0, const float* __restrict__ p1,
    const float* __restrict__ p2, const float* __restrict__ res,
    float* __restrict__ out) {
  const int i = (blockIdx.x * 256 + threadIdx.x) * 4;
  const f32x4 a = *(const f32x4*)&p0[i];
  const f32x4 b = *(const f32x4*)&p1[i];
  const f32x4 c = *(const f32x4*)&p2[i];
  const f32x4 e = *(const f32x4*)&res[i];
  f32x4 o;
#pragma unroll
  for (int k = 0; k < 4; ++k) o[k] = ((a[k] + b[k]) + c[k]) + e[k];
  *(f32x4*)&out[i] = o;
}

// ---------------------------------------------------------------------------
// LayerNorm over D=1024, one token per 256-thread block, bf16 out.
// ---------------------------------------------------------------------------
__global__ __launch_bounds__(256) void ln_kernel(
    const float* __restrict__ x, const float* __restrict__ g,
    const float* __restrict__ be, unsigned short* __restrict__ out) {
  __shared__ float sbuf[4];
  const int t = blockIdx.x, tid = threadIdx.x;
  const float* row = x + (size_t)t * 1024;
  float v[4], s = 0.f;
#pragma unroll
  for (int j = 0; j < 4; ++j) { v[j] = row[tid + j * 256]; s += v[j]; }
#pragma unroll
  for (int off = 32; off; off >>= 1) s += __shfl_xor(s, off);
  if ((tid & 63) == 0) sbuf[tid >> 6] = s;
  __syncthreads();
  const float mu = (sbuf[0] + sbuf[1] + sbuf[2] + sbuf[3]) * (1.f / 1024.f);
  __syncthreads();
  float ss = 0.f;
#pragma unroll
  for (int j = 0; j < 4; ++j) { const float d = v[j] - mu; ss += d * d; }
#pragma unroll
  for (int off = 32; off; off >>= 1) ss += __shfl_xor(ss, off);
  if ((tid & 63) == 0) sbuf[tid >> 6] = ss;
  __syncthreads();
  const float var = (sbuf[0] + sbuf[1] + sbuf[2] + sbuf[3]) * (1.f / 1024.f);
  const float rstd = rsqrtf(var + 1e-5f);
  unsigned short* orow = out + (size_t)t * 1024;
#pragma unroll
  for (int j = 0; j < 4; ++j) {
    const int c = tid + j * 256;
    orow[c] = f2b((v[j] - mu) * rstd * g[c] + be[c]);
  }
}

// ---------------------------------------------------------------------------
// Attention mixing. Phase-2 writes vectorized: uint4 (8 bf16) per store.
// ---------------------------------------------------------------------------
__global__ __launch_bounds__(256) void mix_attn(
    const unsigned short* __restrict__ all_h,
    const float* __restrict__ w_fq, const float* __restrict__ w_fk,
    const float* __restrict__ w_fv, const float* __restrict__ w_rq,
    const float* __restrict__ w_rk, const float* __restrict__ w_rv,
    unsigned short* __restrict__ t_qk, unsigned short* __restrict__ t_v) {
  __shared__ float hq[64], hk[64], hv[64];
  const int t = blockIdx.x, tid = threadIdx.x;
  const int wvi = tid >> 6, lane = tid & 63;
  const unsigned short* row = all_h + (size_t)t * 4096;
  if (wvi < 3) {
    const float* wf = (wvi == 0 ? w_fq : wvi == 1 ? w_fk : w_fv) + (size_t)t * 32;
    const int base = (wvi == 2) ? 2048 : 0;
    float acc = 0.f;
#pragma unroll
    for (int n = 0; n < 32; ++n) acc += wf[n] * b2f(row[base + n * 64 + lane]);
    (wvi == 0 ? hq : wvi == 1 ? hk : hv)[lane] = acc;
  }
  __syncthreads();
  const int n = tid >> 3, r0 = (tid & 7) * 8;
  const float wq = w_rq[(size_t)t * 32 + n];
  const float wk = w_rk[(size_t)t * 32 + n];
  const float wv2 = w_rv[(size_t)t * 32 + n];
  unsigned dq[4], dk[4], dv[4];
#pragma unroll
  for (int jj = 0; jj < 4; ++jj) {
    dq[jj] = pk2(wq * hq[r0 + 2 * jj], wq * hq[r0 + 2 * jj + 1]);
    dk[jj] = pk2(wk * hk[r0 + 2 * jj], wk * hk[r0 + 2 * jj + 1]);
    dv[jj] = pk2(wv2 * hv[r0 + 2 * jj], wv2 * hv[r0 + 2 * jj + 1]);
  }
  *(uint4*)&t_qk[(size_t)t * 2048 + tid * 8] = *(uint4*)dq;
  *(uint4*)&t_qk[(size_t)(4096 + t) * 2048 + tid * 8] = *(uint4*)dk;
  *(uint4*)&t_v[(size_t)t * 2048 + tid * 8] = *(uint4*)dv;
}

// Knowledge mixing (RK=128), vectorized stores
__global__ __launch_bounds__(256) void mix_know(
    const unsigned short* __restrict__ all_h, const float* __restrict__ w_f,
    const float* __restrict__ w_r, unsigned short* __restrict__ t_know) {
  __shared__ float h[128];
  const int t = blockIdx.x, tid = threadIdx.x;
  const unsigned short* row = all_h + (size_t)t * 4096;
  if (tid < 128) {
    const float* wf = w_f + (size_t)t * 32;
    float acc = 0.f;
#pragma unroll
    for (int n = 0; n < 32; ++n) acc += wf[n] * b2f(row[n * 128 + tid]);
    h[tid] = acc;
  }
  __syncthreads();
  const int n = tid >> 3, r0 = (tid & 7) * 16;
  const float wn = w_r[(size_t)t * 32 + n];
  unsigned d[8];
#pragma unroll
  for (int jj = 0; jj < 8; ++jj)
    d[jj] = pk2(wn * h[r0 + 2 * jj], wn * h[r0 + 2 * jj + 1]);
  *(uint4*)&t_know[(size_t)t * 4096 + tid * 16] = *(uint4*)d;
  *(uint4*)&t_know[(size_t)t * 4096 + tid * 16 + 8] = *(uint4*)&d[4];
}

// ---------------------------------------------------------------------------
// Merged weight prep: 6 transposes + W_O convert in ONE dispatch.
// ---------------------------------------------------------------------------
__global__ __launch_bounds__(256) void prep_all(
    const float* __restrict__ f_qk, const float* __restrict__ f_v,
    const float* __restrict__ f_know, const float* __restrict__ r_qk,
    const float* __restrict__ r_v, const float* __restrict__ r_know,
    const float* __restrict__ W_O,
    unsigned short* __restrict__ fcomb, unsigned short* __restrict__ fknowT,
    unsigned short* __restrict__ r_qkT, unsigned short* __restrict__ r_vT,
    unsigned short* __restrict__ r_knowT, unsigned short* __restrict__ WO_bf) {
  __shared__ float tile[32][33];
  const int bid = blockIdx.x;
  const int tx = threadIdx.x, ty = threadIdx.y;
  const float* in;
  unsigned short* out;
  int R, C, gx, loc;
  if (bid < 2048)       { in = f_qk;   out = fcomb;                         R = 1024; C = 64;   gx = 2;  loc = bid; }
  else if (bid < 4096)  { in = f_v;    out = fcomb + (size_t)2048 * 1024;   R = 1024; C = 64;   gx = 2;  loc = bid - 2048; }
  else if (bid < 8192)  { in = f_know; out = fknowT;                        R = 1024; C = 128;  gx = 4;  loc = bid - 4096; }
  else if (bid < 10240) { in = r_qk;   out = r_qkT;                         R = 2048; C = 1024; gx = 32; loc = bid - 8192; }
  else if (bid < 12288) { in = r_v;    out = r_vT;                          R = 2048; C = 1024; gx = 32; loc = bid - 10240; }
  else if (bid < 16384) { in = r_know; out = r_knowT;                       R = 4096; C = 1024; gx = 32; loc = bid - 12288; }
  else {
    const int i = ((bid - 16384) * 256 + ty * 32 + tx) * 4;
    const f32x4 v = *(const f32x4*)&W_O[i];
    *(unsigned*)&WO_bf[i] = pk2(v[0], v[1]);
    *(unsigned*)&WO_bf[i + 2] = pk2(v[2], v[3]);
    return;
  }
  const int tiles = gx * (R >> 5);
  const int bb = loc / tiles, rem = loc % tiles;
  const int r0 = (rem / gx) * 32, c0 = (rem % gx) * 32;
  const float* ip = in + (size_t)bb * R * C;
  unsigned short* op = out + (size_t)bb * R * C;
#pragma unroll
  for (int j = 0; j < 4; ++j)
    tile[ty + j * 8][tx] = ip[(size_t)(r0 + ty + j * 8) * C + c0 + tx];
  __syncthreads();
#pragma unroll
  for (int j = 0; j < 4; ++j)
    op[(size_t)(c0 + ty + j * 8) * R + r0 + tx] = f2b(tile[tx][ty + j * 8]);
}

// ---------------------------------------------------------------------------
// Causal flash attention: SPLIT-K over history, uniform work units.
// v9: branch-free fast path (diag tile handled once, outside the k-loop);
// f32x4 packed softmax math; LDS staging kept (dedups K/V requests 4x).
// ---------------------------------------------------------------------------
__global__ __launch_bounds__(256) void flash_split(
    const unsigned short* __restrict__ Q, const unsigned short* __restrict__ Kp,
    const unsigned short* __restrict__ VT, unsigned short* __restrict__ O,
    float* __restrict__ Opart, float* __restrict__ ml) {
  __shared__ unsigned short Kls[2][64 * 64];
  __shared__ unsigned short Vls[2][64 * 64];
  const int uidx = 79 - (int)blockIdx.x;
  int uu = uidx, qt = 0, ch = 0;
  for (int q = 0; q < 32; ++q) {
    const int n = (q >> 3) + 1;
    if (uu < n) { qt = q; ch = uu; break; }
    uu -= n;
  }
  const int bh = blockIdx.y;
  const int b = bh >> 4, h = bh & 15;
  const int tid = threadIdx.x;
  const int w = tid >> 6, lane = tid & 63, quad = lane >> 4, l16 = lane & 15;
  const int tb = b * 2048;
  const int qrow = qt * 64 + w * 16;
  const int ktlo = ch * 8;
  const int kthi = min(qt, ch * 8 + 7);
  const float C = 0.18033688f;  // (1/sqrt(64)) * log2(e)

  const int srow = (lane >> 3);
  const int scol = ((lane & 7) ^ srow) * 8;

  bf16x8 qf[2];
#pragma unroll
  for (int kk = 0; kk < 2; ++kk)
    qf[kk] = *(const bf16x8*)&Q[(size_t)(tb + qrow + l16) * 1024 + h * 64 + kk * 32 + quad * 8];

  const f32x4 fz = {0.f, 0.f, 0.f, 0.f};
  float m_i = -1e30f, l_i = 0.f;
  f32x4 o_acc[4];
#pragma unroll
  for (int nt = 0; nt < 4; ++nt) o_acc[nt] = fz;

  auto stage = [&](int buf, int kt) {
#pragma unroll
    for (int j = 0; j < 2; ++j) {
      const int rg = (w * 2 + j) * 8 + srow;
      __builtin_amdgcn_global_load_lds(
          (const __attribute__((address_space(1))) unsigned int*)
              (Kp + (size_t)(tb + kt * 64 + rg) * 1024 + h * 64 + scol),
          (__attribute__((address_space(3))) unsigned int*)&Kls[buf][(w * 2 + j) * 8 * 64],
          16, 0, 0);
      __builtin_amdgcn_global_load_lds(
          (const __attribute__((address_space(1))) unsigned int*)
              (VT + (size_t)(h * 64 + rg) * 4096 + tb + kt * 64 + scol),
          (__attribute__((address_space(3))) unsigned int*)&Vls[buf][(w * 2 + j) * 8 * 64],
          16, 0, 0);
    }
  };

  const int srcA = (((quad & 1) * 32 + l16) << 2);
  const int srcB = srcA + 64;
  const bool hiq = (quad >= 2);

  // pack P -> bf16, redistribute across quads, run PV MFMAs, fold l.
  auto pv_block = [&](f32x4* s, bf16x8* vf, const f32x4& rsv) {
    unsigned pk[4][2];
#pragma unroll
    for (int nt = 0; nt < 4; ++nt) {
      pk[nt][0] = pkt(s[nt][0], s[nt][1]);
      pk[nt][1] = pkt(s[nt][2], s[nt][3]);
    }
#pragma unroll
    for (int kk = 0; kk < 2; ++kk) {
      const int ea = 2 * kk, eb = 2 * kk + 1;
      const unsigned u0 = __builtin_amdgcn_ds_bpermute(srcA, pk[ea][0]);
      const unsigned u1 = __builtin_amdgcn_ds_bpermute(srcA, pk[ea][1]);
      const unsigned u2 = __builtin_amdgcn_ds_bpermute(srcB, pk[ea][0]);
      const unsigned u3 = __builtin_amdgcn_ds_bpermute(srcB, pk[ea][1]);
      const unsigned w0 = __builtin_amdgcn_ds_bpermute(srcA, pk[eb][0]);
      const unsigned w1 = __builtin_amdgcn_ds_bpermute(srcA, pk[eb][1]);
      const unsigned w2 = __builtin_amdgcn_ds_bpermute(srcB, pk[eb][0]);
      const unsigned w3 = __builtin_amdgcn_ds_bpermute(srcB, pk[eb][1]);
      unsigned dw[4];
      dw[0] = hiq ? w0 : u0;
      dw[1] = hiq ? w1 : u1;
      dw[2] = hiq ? w2 : u2;
      dw[3] = hiq ? w3 : u3;
      const bf16x8 pf = *(const bf16x8*)dw;
      __builtin_amdgcn_s_setprio(1);
#pragma unroll
      for (int nt = 0; nt < 4; ++nt)
        o_acc[nt] = __builtin_amdgcn_mfma_f32_16x16x32_bf16(vf[kk * 4 + nt], pf, o_acc[nt], 0, 0, 0);
      __builtin_amdgcn_s_setprio(0);
    }
    float rs = (rsv[0] + rsv[1]) + (rsv[2] + rsv[3]);
    rs += __shfl_xor(rs, 16);
    rs += __shfl_xor(rs, 32);
    l_i += rs;
  };

  stage(0, ktlo);
  __syncthreads();
  int buf = 0;

  const bool hasdiag = (ch == (qt >> 3));
  const int ktnd = hasdiag ? kthi - 1 : kthi;  // last non-diag tile

  // ---- fast path: branch-free, no masking ----
  for (int kt = ktlo; kt <= ktnd; ++kt) {
    if (kt < kthi) stage(buf ^ 1, kt + 1);
    bf16x8 kf[8], vf[8];
#pragma unroll
    for (int kk = 0; kk < 2; ++kk)
#pragma unroll
      for (int nt = 0; nt < 4; ++nt) {
        const int sl = (((kk * 4 + quad) ^ (l16 & 7)) * 8);
        kf[kk * 4 + nt] = *(const bf16x8*)&Kls[buf][(nt * 16 + l16) * 64 + sl];
        vf[kk * 4 + nt] = *(const bf16x8*)&Vls[buf][(nt * 16 + l16) * 64 + sl];
      }

    f32x4 s[4];
    __builtin_amdgcn_s_setprio(1);
#pragma unroll
    for (int nt = 0; nt < 4; ++nt)
      s[nt] = __builtin_amdgcn_mfma_f32_16x16x32_bf16(kf[nt], qf[0], fz, 0, 0, 0);
#pragma unroll
    for (int nt = 0; nt < 4; ++nt)
      s[nt] = __builtin_amdgcn_mfma_f32_16x16x32_bf16(kf[4 + nt], qf[1], s[nt], 0, 0, 0);
    __builtin_amdgcn_s_setprio(0);

    const f32x4 m4 = vmax4(vmax4(s[0], s[1]), vmax4(s[2], s[3]));
    float mx = fmaxf(fmaxf(m4[0], m4[1]), fmaxf(m4[2], m4[3]));
    mx = fmaxf(mx, __shfl_xor(mx, 16));
    mx = fmaxf(mx, __shfl_xor(mx, 32));
    if (!__all(mx <= m_i)) {
      const float mn = fmaxf(m_i, mx);
      const float al = exp2f((m_i - mn) * C);
      m_i = mn;
      l_i *= al;
#pragma unroll
      for (int nt = 0; nt < 4; ++nt) o_acc[nt] *= al;
    }
    const float mC = m_i * C;
    f32x4 rsv = fz;
#pragma unroll
    for (int nt = 0; nt < 4; ++nt) {
      f32x4 e = s[nt] * C - mC;  // v_pk_fma_f32 x2
      f32x4 p;
#pragma unroll
      for (int i = 0; i < 4; ++i) p[i] = exp2f(e[i]);
      s[nt] = p;
      rsv += p;                  // v_pk_add_f32 x2
    }
    pv_block(s, vf, rsv);
    __syncthreads();
    buf ^= 1;
  }

  // ---- diagonal tile (at most once per block) ----
  if (hasdiag) {
    bf16x8 kf[8], vf[8];
#pragma unroll
    for (int kk = 0; kk < 2; ++kk)
#pragma unroll
      for (int nt = 0; nt < 4; ++nt) {
        const int sl = (((kk * 4 + quad) ^ (l16 & 7)) * 8);
        kf[kk * 4 + nt] = *(const bf16x8*)&Kls[buf][(nt * 16 + l16) * 64 + sl];
        vf[kk * 4 + nt] = *(const bf16x8*)&Vls[buf][(nt * 16 + l16) * 64 + sl];
      }
    const int ntmax = w + 1;  // wave-uniform live nt count
    f32x4 s[4];
#pragma unroll
    for (int nt = 0; nt < 4; ++nt) s[nt] = fz;
    __builtin_amdgcn_s_setprio(1);
#pragma unroll
    for (int kk = 0; kk < 2; ++kk)
#pragma unroll
      for (int nt = 0; nt < 4; ++nt)
        if (nt < ntmax)
          s[nt] = __builtin_amdgcn_mfma_f32_16x16x32_bf16(kf[kk * 4 + nt], qf[kk], s[nt], 0, 0, 0);
    __builtin_amdgcn_s_setprio(0);

    const int qloc = w * 16 + l16;
    float mxs[4] = {-1e30f, -1e30f, -1e30f, -1e30f};
#pragma unroll
    for (int nt = 0; nt < 4; ++nt) {
      if (nt >= ntmax) continue;
#pragma unroll
      for (int i = 0; i < 4; ++i) {
        float v = s[nt][i];
        if ((nt * 16 + quad * 4 + i) > qloc) v = -1e30f;
        s[nt][i] = v;
        mxs[nt] = fmaxf(mxs[nt], v);
      }
    }
    float mx = fmaxf(fmaxf(mxs[0], mxs[1]), fmaxf(mxs[2], mxs[3]));
    mx = fmaxf(mx, __shfl_xor(mx, 16));
    mx = fmaxf(mx, __shfl_xor(mx, 32));
    if (!__all(mx <= m_i)) {
      const float mn = fmaxf(m_i, mx);
      const float al = exp2f((m_i - mn) * C);
      m_i = mn;
      l_i *= al;
#pragma unroll
      for (int nt = 0; nt < 4; ++nt) o_acc[nt] *= al;
    }
    const float mC = m_i * C;
    f32x4 rsv = fz;
#pragma unroll
    for (int nt = 0; nt < 4; ++nt) {
      if (nt >= ntmax) { s[nt] = fz; continue; }
      f32x4 e = s[nt] * C - mC;
      f32x4 p;
#pragma unroll
      for (int i = 0; i < 4; ++i) p[i] = exp2f(e[i]);
      s[nt] = p;
      rsv += p;
    }
    pv_block(s, vf, rsv);
  }

  const int nch = (qt >> 3) + 1;
  if (nch == 1) {
    const float inv = 1.0f / l_i;
    unsigned short* orow = O + (size_t)(tb + qrow + l16) * 1024 + h * 64;
#pragma unroll
    for (int nt = 0; nt < 4; ++nt) {
      const unsigned d0 = pk2(o_acc[nt][0] * inv, o_acc[nt][1] * inv);
      const unsigned d1 = pk2(o_acc[nt][2] * inv, o_acc[nt][3] * inv);
      *(unsigned*)&orow[nt * 16 + quad * 4] = d0;
      *(unsigned*)&orow[nt * 16 + quad * 4 + 2] = d1;
    }
  } else {
    const int slot = bh * 80 + uidx;
    const int lq = w * 16 + l16;
    float* op = Opart + ((size_t)slot * 64 + lq) * 64;
#pragma unroll
    for (int nt = 0; nt < 4; ++nt)
      *(f32x4*)&op[nt * 16 + quad * 4] = o_acc[nt];
    if (quad == 0) {
      ml[(size_t)slot * 128 + lq * 2] = m_i;
      ml[(size_t)slot * 128 + lq * 2 + 1] = l_i;
    }
  }
}

// ---------------------------------------------------------------------------
// Combine flash split-K partials for qt in [8,31]. Grid (24, 32).
// ---------------------------------------------------------------------------
__global__ __launch_bounds__(256) void flash_reduce(
    const float* __restrict__ Opart, const float* __restrict__ ml,
    unsigned short* __restrict__ O) {
  const int qt = 8 + blockIdx.x;
  const int bh = blockIdx.y;
  const int b = bh >> 4, h = bh & 15;
  const int j = qt >> 3;
  const int base = 8 * (j * (j + 1) / 2) + (qt - 8 * j) * (j + 1);
  const int nch = j + 1;
  const int tid = threadIdx.x;
  const int lq = tid >> 2, dq = (tid & 3) * 16;
  const float C = 0.18033688f;

  float mc[4], lc[4];
  float m = -1e30f;
#pragma unroll
  for (int c = 0; c < 4; ++c) {
    if (c < nch) {
      const size_t sl = (size_t)(bh * 80 + base + c) * 128 + lq * 2;
      mc[c] = ml[sl];
      lc[c] = ml[sl + 1];
    } else { mc[c] = -1e30f; lc[c] = 0.f; }
    m = fmaxf(m, mc[c]);
  }
  float fac[4], lt = 0.f;
#pragma unroll
  for (int c = 0; c < 4; ++c) {
    fac[c] = (c < nch) ? exp2f((mc[c] - m) * C) : 0.f;
    lt += fac[c] * lc[c];
  }
  const float inv = 1.0f / lt;
  float acc[16];
#pragma unroll
  for (int i = 0; i < 16; ++i) acc[i] = 0.f;
#pragma unroll
  for (int c = 0; c < 4; ++c) {
    if (c >= nch) continue;
    const float* op = Opart + ((size_t)(bh * 80 + base + c) * 64 + lq) * 64 + dq;
#pragma unroll
    for (int i = 0; i < 16; i += 4) {
      const f32x4 v = *(const f32x4*)&op[i];
#pragma unroll
      for (int k = 0; k < 4; ++k) acc[i + k] += fac[c] * v[k];
    }
  }
  unsigned short* orow = O + (size_t)(b * 2048 + qt * 64 + lq) * 1024 + h * 64 + dq;
#pragma unroll
  for (int i = 0; i < 16; i += 2)
    *(unsigned*)&orow[i] = pk2(acc[i] * inv, acc[i + 1] * inv);
}

// ---------------------------------------------------------------------------
extern "C" void kernel_launch(void* const* d_in, const int* in_sizes, int n_in,
                              void* d_out, int out_size, void* d_ws, size_t ws_size,
                              hipStream_t stream) {
  (void)in_sizes; (void)n_in; (void)out_size; (void)ws_size;
  const float* x      = (const float*)d_in[0];
  const float* f_qk   = (const float*)d_in[1];
  const float* f_v    = (const float*)d_in[2];
  const float* r_qk   = (const float*)d_in[3];
  const float* r_v    = (const float*)d_in[4];
  const float* f_know = (const float*)d_in[5];
  const float* r_know = (const float*)d_in[6];
  const float* W_O    = (const float*)d_in[7];
  const float* gamma1 = (const float*)d_in[8];
  const float* beta1  = (const float*)d_in[9];
  const float* gamma2 = (const float*)d_in[10];
  const float* beta2  = (const float*)d_in[11];
  const float* w_fq   = (const float*)d_in[12];
  const float* w_fk   = (const float*)d_in[13];
  const float* w_fv   = (const float*)d_in[14];
  const float* w_rq   = (const float*)d_in[15];
  const float* w_rk   = (const float*)d_in[16];
  const float* w_rv   = (const float*)d_in[17];
  const float* w_kf   = (const float*)d_in[18];
  const float* w_kr   = (const float*)d_in[19];

  char* base = (char*)d_ws;
  size_t off = 0;
  auto alloc = [&](size_t b) { char* p = base + off; off += (b + 255) & ~(size_t)255; return p; };
  unsigned short* fcomb   = (unsigned short*)alloc(8388608);   // [4096][1024]
  unsigned short* fknowT  = (unsigned short*)alloc(8388608);   // [4096][1024]
  unsigned short* r_qkT   = (unsigned short*)alloc(4194304);   // [1024][2048]
  unsigned short* r_vT    = (unsigned short*)alloc(4194304);   // [1024][2048]
  unsigned short* r_knowT = (unsigned short*)alloc(8388608);   // [1024][4096]
  unsigned short* WO_bf   = (unsigned short*)alloc(2097152);   // [1024][1024]
  unsigned short* nx_bf   = (unsigned short*)alloc(8388608);   // [4096][1024]
  unsigned short* all_h   = (unsigned short*)alloc(33554432);  // [4096][4096]
  unsigned short* t_qk    = (unsigned short*)alloc(33554432);  // [8192][2048]
  unsigned short* t_v     = (unsigned short*)alloc(16777216);  // [4096][2048]; reused as x1 fp32
  unsigned short* QKbuf   = (unsigned short*)alloc(16777216);  // [8192][1024]
  unsigned short* VT      = (unsigned short*)alloc(8388608);   // [1024][4096]
  unsigned short* attn    = (unsigned short*)alloc(8388608);   // [4096][1024]
  float* x1 = (float*)t_v;                    // t_v dead before x1 written
  float* Opart = (float*)all_h;               // flash partials (spills into t_qk, dead)
  float* mlbuf = (float*)((char*)all_h + 41943040);
  float* pW0 = (float*)all_h;                 // ks3 fp32 partials (knowledge)
  float* pW1 = (float*)((char*)all_h + 16777216);
  float* pW2 = (float*)QKbuf;

  const dim3 blk256(256), blk512(512), blkT(32, 8);

  prep_all<<<17408, blkT, 0, stream>>>(f_qk, f_v, f_know, r_qk, r_v, r_know, W_O,
                                       fcomb, fknowT, r_qkT, r_vT, r_knowT, WO_bf);

  // attention circuit
  ln_kernel<<<4096, blk256, 0, stream>>>(x, gamma1, beta1, nx_bf);
  gemm_bt256<<<256, blk512, 0, stream>>>(nx_bf, fcomb, all_h, 1024);
  mix_attn<<<4096, blk256, 0, stream>>>(all_h, w_fq, w_fk, w_fv, w_rq, w_rk, w_rv, t_qk, t_v);
  gemm_qkv<<<768, blk256, 0, stream>>>(t_qk, t_v, r_qkT, r_vT, QKbuf, VT);
  flash_split<<<dim3(80, 32), blk256, 0, stream>>>(QKbuf, QKbuf + (size_t)4096 * 1024, VT, attn,
                                                   Opart, mlbuf);
  flash_reduce<<<dim3(24, 32), blk256, 0, stream>>>(Opart, mlbuf, attn);
  gemm_wo_res<<<512, blk256, 0, stream>>>(attn, WO_bf, x, x1);

  // knowledge circuit
  ln_kernel<<<4096, blk256, 0, stream>>>(x1, gamma2, beta2, nx_bf);
  gemm_bt256<<<256, blk512, 0, stream>>>(nx_bf, fknowT, all_h, 1024);
  mix_know<<<4096, blk256, 0, stream>>>(all_h, w_kf, w_kr, t_qk);
  gemm_ks3<<<768, blk256, 0, stream>>>(t_qk, r_knowT, pW0, pW1, pW2);
  reduce_add4<<<4096, blk256, 0, stream>>>(pW0, pW1, pW2, x1, (float*)d_out);
}